// Round 3
// baseline (75.021 us; speedup 1.0000x reference)
//
#include <hip/hip_runtime.h>

#define QT 4
#define NM 1600
#define NG (NM / 4)   // 400 groups of 4 targets
#define NC 91
#define BLOCK 256

__global__ __launch_bounds__(BLOCK, 8) void matcher_cost_kernel(
    const float* __restrict__ logits,   // [BQ, 91]
    const float* __restrict__ pboxes,   // [BQ, 4] cxcywh
    const int*   __restrict__ tlabels,  // [1600]
    const float* __restrict__ tboxes,   // [1600, 4] cxcywh
    float* __restrict__ out)            // [BQ, 1600]
{
    // Only the per-block softmax needs LDS (1.5 KB). Targets are identical
    // for all blocks and L1-resident -> read straight from global.
    __shared__ float s_prob[QT][NC + 1];

    const int tid = threadIdx.x;
    const int q0  = blockIdx.x * QT;

    // per-wave softmax: wave w handles query q0+w (91 classes over 64 lanes)
    {
        const int w = tid >> 6, lane = tid & 63;
        const float* lrow = logits + (size_t)(q0 + w) * NC;
        float v0 = (lane      < NC) ? lrow[lane]      : -3.4e38f;
        float v1 = (lane + 64 < NC) ? lrow[lane + 64] : -3.4e38f;
        float mx = fmaxf(v0, v1);
        #pragma unroll
        for (int off = 32; off; off >>= 1) mx = fmaxf(mx, __shfl_xor(mx, off));
        float e0 = (lane      < NC) ? __expf(v0 - mx) : 0.0f;
        float e1 = (lane + 64 < NC) ? __expf(v1 - mx) : 0.0f;
        float s = e0 + e1;
        #pragma unroll
        for (int off = 32; off; off >>= 1) s += __shfl_xor(s, off);
        float inv = 1.0f / s;
        if (lane      < NC) s_prob[w][lane]      = e0 * inv;
        if (lane + 64 < NC) s_prob[w][lane + 64] = e1 * inv;
    }

    // query constants in registers
    float qcx[QT], qcy[QT], qw[QT], qh[QT];
    float qx0[QT], qy0[QT], qx1[QT], qy1[QT], qa[QT];
    #pragma unroll
    for (int wq = 0; wq < QT; ++wq) {
        float4 pb = ((const float4*)pboxes)[q0 + wq];
        qcx[wq] = pb.x; qcy[wq] = pb.y; qw[wq] = pb.z; qh[wq] = pb.w;
        qx0[wq] = pb.x - 0.5f * pb.z; qy0[wq] = pb.y - 0.5f * pb.w;
        qx1[wq] = pb.x + 0.5f * pb.z; qy1[wq] = pb.y + 0.5f * pb.w;
        qa[wq]  = pb.z * pb.w;
    }

    __syncthreads();

    // sweep: load a 4-target group from global (L1-hit), reuse for QT queries
    const float4* tb4 = (const float4*)tboxes;
    const int4*   lb4 = (const int4*)tlabels;
    for (int g = tid; g < NG; g += BLOCK) {
        float4 t[4];
        t[0] = tb4[4 * g + 0]; t[1] = tb4[4 * g + 1];
        t[2] = tb4[4 * g + 2]; t[3] = tb4[4 * g + 3];
        int4 vl = lb4[g];
        int lab[4] = {vl.x, vl.y, vl.z, vl.w};
        float tx0[4], ty0[4], tx1[4], ty1[4], ta[4];
        #pragma unroll
        for (int j = 0; j < 4; ++j) {
            tx0[j] = t[j].x - 0.5f * t[j].z;
            ty0[j] = t[j].y - 0.5f * t[j].w;
            tx1[j] = t[j].x + 0.5f * t[j].z;
            ty1[j] = t[j].y + 0.5f * t[j].w;
            ta[j]  = t[j].z * t[j].w;
        }
        #pragma unroll
        for (int wq = 0; wq < QT; ++wq) {
            float r[4];
            #pragma unroll
            for (int j = 0; j < 4; ++j) {
                // L1 on cxcywh
                float l1 = fabsf(qcx[wq] - t[j].x) + fabsf(qcy[wq] - t[j].y)
                         + fabsf(qw[wq]  - t[j].z) + fabsf(qh[wq]  - t[j].w);
                // intersection (raw, before clamp)
                float ix0 = fmaxf(qx0[wq], tx0[j]);
                float ix1 = fminf(qx1[wq], tx1[j]);
                float iy0 = fmaxf(qy0[wq], ty0[j]);
                float iy1 = fminf(qy1[wq], ty1[j]);
                float iwr = ix1 - ix0, ihr = iy1 - iy0;
                float iw = fmaxf(iwr, 0.0f), ih = fmaxf(ihr, 0.0f);
                float inter = iw * ih;
                float uni = qa[wq] + ta[j] - inter;
                // enclosing via min+max = sum identity: ew = qw + tw - iwr
                float ew = qw[wq] + t[j].z - iwr;
                float eh = qh[wq] + t[j].w - ihr;
                float earea = ew * eh;
                // X = inter/uni + uni/earea, one rcp
                float rr = __builtin_amdgcn_rcpf(uni * earea);
                float X = fmaf(uni, uni, inter * earea) * rr;
                // C = 5*l1 - cls + 2 - 2*X
                float c2 = 2.0f - s_prob[wq][lab[j]];
                r[j] = fmaf(-2.0f, X, fmaf(5.0f, l1, c2));
            }
            ((float4*)(out + (size_t)(q0 + wq) * NM))[g] =
                make_float4(r[0], r[1], r[2], r[3]);
        }
    }
}

extern "C" void kernel_launch(void* const* d_in, const int* in_sizes, int n_in,
                              void* d_out, int out_size, void* d_ws, size_t ws_size,
                              hipStream_t stream) {
    const float* logits  = (const float*)d_in[0];
    const float* pboxes  = (const float*)d_in[1];
    const int*   tlabels = (const int*)d_in[2];
    const float* tboxes  = (const float*)d_in[3];
    float* out = (float*)d_out;

    const int BQ = in_sizes[1] / 4;   // 14400
    const int grid = BQ / QT;         // 3600
    matcher_cost_kernel<<<grid, BLOCK, 0, stream>>>(logits, pboxes, tlabels, tboxes, out);
}

// Round 4
// 33.385 us; speedup vs baseline: 2.2472x; 2.2472x over previous
//
#include <hip/hip_runtime.h>

#define QT 8             // queries per block (2 per wave)
#define NM 1600
#define NG (NM / 4)      // 400 groups of 4 targets
#define NC 91
#define BLOCK 256

__global__ __launch_bounds__(BLOCK, 5) void matcher_cost_kernel(
    const float* __restrict__ logits,   // [BQ, 91]
    const float* __restrict__ pboxes,   // [BQ, 4] cxcywh
    const int*   __restrict__ tlabels,  // [1600]
    const float* __restrict__ tboxes,   // [1600, 4] cxcywh
    float* __restrict__ out)            // [BQ, 1600]
{
    // SoA target staging (16B-lane-stride ds_read_b128, conflict-free),
    // labels packed to u8, per-block softmax table. ~30.1 KB -> 5 blocks/CU.
    __shared__ float4 s_cx[NG], s_cy[NG], s_w[NG], s_h[NG];  // 25600 B
    __shared__ unsigned s_lab[NG];                           // 1600 B
    __shared__ float s_prob[QT][NC + 1];                     // 2944 B

    const int tid  = threadIdx.x;
    const int wv   = tid >> 6;      // wave 0..3
    const int lane = tid & 63;
    const int q0   = blockIdx.x * QT;

    // ---- stage targets AoS -> SoA, labels -> packed u8 ----
    const float4* tb4 = (const float4*)tboxes;
    const int4*   lb4 = (const int4*)tlabels;
    for (int g = tid; g < NG; g += BLOCK) {
        float4 t0 = tb4[4 * g + 0], t1 = tb4[4 * g + 1];
        float4 t2 = tb4[4 * g + 2], t3 = tb4[4 * g + 3];
        s_cx[g] = make_float4(t0.x, t1.x, t2.x, t3.x);
        s_cy[g] = make_float4(t0.y, t1.y, t2.y, t3.y);
        s_w[g]  = make_float4(t0.z, t1.z, t2.z, t3.z);
        s_h[g]  = make_float4(t0.w, t1.w, t2.w, t3.w);
        int4 vl = lb4[g];
        s_lab[g] = (unsigned)(vl.x & 0xff) | ((unsigned)(vl.y & 0xff) << 8)
                 | ((unsigned)(vl.z & 0xff) << 16) | ((unsigned)(vl.w & 0xff) << 24);
    }

    // ---- softmax: wave wv computes queries q0+2*wv and q0+2*wv+1 ----
    #pragma unroll
    for (int k = 0; k < 2; ++k) {
        const int ql = 2 * wv + k;
        const float* lrow = logits + (size_t)(q0 + ql) * NC;
        float v0 = (lane      < NC) ? lrow[lane]      : -3.4e38f;
        float v1 = (lane + 64 < NC) ? lrow[lane + 64] : -3.4e38f;
        float mx = fmaxf(v0, v1);
        #pragma unroll
        for (int off = 32; off; off >>= 1) mx = fmaxf(mx, __shfl_xor(mx, off));
        float e0 = (lane      < NC) ? __expf(v0 - mx) : 0.0f;
        float e1 = (lane + 64 < NC) ? __expf(v1 - mx) : 0.0f;
        float s = e0 + e1;
        #pragma unroll
        for (int off = 32; off; off >>= 1) s += __shfl_xor(s, off);
        float inv = 1.0f / s;
        if (lane      < NC) s_prob[ql][lane]      = e0 * inv;
        if (lane + 64 < NC) s_prob[ql][lane + 64] = e1 * inv;
    }

    // ---- query constants for this wave's 2 queries ----
    float qcx[2], qcy[2], qww[2], qhh[2], qhw[2], qhh2[2], qa[2];
    #pragma unroll
    for (int k = 0; k < 2; ++k) {
        float4 pb = ((const float4*)pboxes)[q0 + 2 * wv + k];
        qcx[k] = pb.x; qcy[k] = pb.y; qww[k] = pb.z; qhh[k] = pb.w;
        qhw[k] = 0.5f * pb.z; qhh2[k] = 0.5f * pb.w;
        qa[k]  = pb.z * pb.w;
    }

    __syncthreads();

    // ---- sweep: each wave handles its 2 queries over all target groups ----
    for (int g = lane; g < NG; g += 64) {
        float4 vcx = s_cx[g], vcy = s_cy[g], vw = s_w[g], vh = s_h[g];
        unsigned labw = s_lab[g];
        float tcx[4] = {vcx.x, vcx.y, vcx.z, vcx.w};
        float tcy[4] = {vcy.x, vcy.y, vcy.z, vcy.w};
        float tw[4]  = {vw.x,  vw.y,  vw.z,  vw.w};
        float th[4]  = {vh.x,  vh.y,  vh.z,  vh.w};
        float ta[4];
        #pragma unroll
        for (int j = 0; j < 4; ++j) ta[j] = tw[j] * th[j];

        #pragma unroll
        for (int k = 0; k < 2; ++k) {
            const int ql = 2 * wv + k;
            float r[4];
            #pragma unroll
            for (int j = 0; j < 4; ++j) {
                float dx = qcx[k] - tcx[j], dy = qcy[k] - tcy[j];
                float dw = qww[k] - tw[j],  dh = qhh[k] - th[j];
                float adx = fabsf(dx), ady = fabsf(dy);
                float adw = fabsf(dw), adh = fabsf(dh);
                float l1 = (adx + ady) + (adw + adh);
                // interval identity: overlap_raw = s - max(ad_center, ad_len/2)
                //                    enclose     = s + max(ad_center, ad_len/2)
                float sx = fmaf(0.5f, tw[j], qhw[k]);
                float sy = fmaf(0.5f, th[j], qhh2[k]);
                float mxx = fmaxf(adx, 0.5f * adw);
                float mxy = fmaxf(ady, 0.5f * adh);
                float iwr = sx - mxx, ihr = sy - mxy;
                float iw = fmaxf(iwr, 0.0f), ih = fmaxf(ihr, 0.0f);
                float inter = iw * ih;
                float ew = sx + mxx, eh = sy + mxy;
                float earea = ew * eh;
                float uni = (qa[k] + ta[j]) - inter;
                // X = inter/uni + uni/earea with a single rcp
                float rr = __builtin_amdgcn_rcpf(uni * earea);
                float X = fmaf(uni, uni, inter * earea) * rr;
                float cls = s_prob[ql][(labw >> (8 * j)) & 0xff];
                r[j] = fmaf(-2.0f, X, fmaf(5.0f, l1, 2.0f - cls));
            }
            ((float4*)(out + (size_t)(q0 + ql) * NM))[g] =
                make_float4(r[0], r[1], r[2], r[3]);
        }
    }
}

extern "C" void kernel_launch(void* const* d_in, const int* in_sizes, int n_in,
                              void* d_out, int out_size, void* d_ws, size_t ws_size,
                              hipStream_t stream) {
    const float* logits  = (const float*)d_in[0];
    const float* pboxes  = (const float*)d_in[1];
    const int*   tlabels = (const int*)d_in[2];
    const float* tboxes  = (const float*)d_in[3];
    float* out = (float*)d_out;

    const int BQ = in_sizes[1] / 4;   // 14400
    const int grid = BQ / QT;         // 1800
    matcher_cost_kernel<<<grid, BLOCK, 0, stream>>>(logits, pboxes, tlabels, tboxes, out);
}

// Round 6
// 31.229 us; speedup vs baseline: 2.4023x; 1.0691x over previous
//
#include <hip/hip_runtime.h>

#define QT 8             // queries per block (2 per wave)
#define NM 1600
#define NG (NM / 4)      // 400 groups of 4 targets
#define NC 91
#define BLOCK 256

typedef float f32x4 __attribute__((ext_vector_type(4)));

__global__ __launch_bounds__(BLOCK, 5) void matcher_cost_kernel(
    const float* __restrict__ logits,   // [BQ, 91]
    const float* __restrict__ pboxes,   // [BQ, 4] cxcywh
    const int*   __restrict__ tlabels,  // [1600]
    const float* __restrict__ tboxes,   // [1600, 4] cxcywh
    float* __restrict__ out)            // [BQ, 1600]
{
    // SoA target staging with HALF-widths (saves per-pair 0.5x muls),
    // labels packed u8, per-block softmax table. ~30.1 KB -> 5 blocks/CU.
    __shared__ float4 s_cx[NG], s_cy[NG], s_hw[NG], s_hh[NG]; // 25600 B
    __shared__ unsigned s_lab[NG];                            // 1600 B
    __shared__ float s_prob[QT][NC + 1];                      // 2944 B

    const int tid  = threadIdx.x;
    const int wv   = tid >> 6;      // wave 0..3
    const int lane = tid & 63;
    const int q0   = blockIdx.x * QT;

    // ---- stage targets AoS -> SoA (half-widths), labels -> packed u8 ----
    const float4* tb4 = (const float4*)tboxes;
    const int4*   lb4 = (const int4*)tlabels;
    for (int g = tid; g < NG; g += BLOCK) {
        float4 t0 = tb4[4 * g + 0], t1 = tb4[4 * g + 1];
        float4 t2 = tb4[4 * g + 2], t3 = tb4[4 * g + 3];
        s_cx[g] = make_float4(t0.x, t1.x, t2.x, t3.x);
        s_cy[g] = make_float4(t0.y, t1.y, t2.y, t3.y);
        s_hw[g] = make_float4(0.5f * t0.z, 0.5f * t1.z, 0.5f * t2.z, 0.5f * t3.z);
        s_hh[g] = make_float4(0.5f * t0.w, 0.5f * t1.w, 0.5f * t2.w, 0.5f * t3.w);
        int4 vl = lb4[g];
        s_lab[g] = (unsigned)(vl.x & 0xff) | ((unsigned)(vl.y & 0xff) << 8)
                 | ((unsigned)(vl.z & 0xff) << 16) | ((unsigned)(vl.w & 0xff) << 24);
    }

    // ---- softmax: wave wv computes queries q0+2*wv and q0+2*wv+1 ----
    #pragma unroll
    for (int k = 0; k < 2; ++k) {
        const int ql = 2 * wv + k;
        const float* lrow = logits + (size_t)(q0 + ql) * NC;
        float v0 = (lane      < NC) ? lrow[lane]      : -3.4e38f;
        float v1 = (lane + 64 < NC) ? lrow[lane + 64] : -3.4e38f;
        float mx = fmaxf(v0, v1);
        #pragma unroll
        for (int off = 32; off; off >>= 1) mx = fmaxf(mx, __shfl_xor(mx, off));
        float e0 = (lane      < NC) ? __expf(v0 - mx) : 0.0f;
        float e1 = (lane + 64 < NC) ? __expf(v1 - mx) : 0.0f;
        float s = e0 + e1;
        #pragma unroll
        for (int off = 32; off; off >>= 1) s += __shfl_xor(s, off);
        float inv = 1.0f / s;
        if (lane      < NC) s_prob[ql][lane]      = e0 * inv;
        if (lane + 64 < NC) s_prob[ql][lane + 64] = e1 * inv;
    }

    // ---- query constants (half-width form) for this wave's 2 queries ----
    float qcx[2], qcy[2], qhw[2], qhh[2], qa[2];
    #pragma unroll
    for (int k = 0; k < 2; ++k) {
        float4 pb = ((const float4*)pboxes)[q0 + 2 * wv + k];
        qcx[k] = pb.x; qcy[k] = pb.y;
        qhw[k] = 0.5f * pb.z; qhh[k] = 0.5f * pb.w;
        qa[k]  = pb.z * pb.w;
    }

    __syncthreads();

    // ---- sweep: each wave handles its 2 queries over all target groups ----
    for (int g = lane; g < NG; g += 64) {
        float4 vcx = s_cx[g], vcy = s_cy[g], vhw = s_hw[g], vhh = s_hh[g];
        unsigned labw = s_lab[g];
        float tcx[4] = {vcx.x, vcx.y, vcx.z, vcx.w};
        float tcy[4] = {vcy.x, vcy.y, vcy.z, vcy.w};
        float thw[4] = {vhw.x, vhw.y, vhw.z, vhw.w};
        float thh[4] = {vhh.x, vhh.y, vhh.z, vhh.w};
        float ta[4];
        #pragma unroll
        for (int j = 0; j < 4; ++j) ta[j] = 4.0f * (thw[j] * thh[j]);

        #pragma unroll
        for (int k = 0; k < 2; ++k) {
            const int ql = 2 * wv + k;
            f32x4 r;
            #pragma unroll
            for (int j = 0; j < 4; ++j) {
                float adx  = fabsf(qcx[k] - tcx[j]);
                float ady  = fabsf(qcy[k] - tcy[j]);
                float adwh = fabsf(qhw[k] - thw[j]);
                float adhh = fabsf(qhh[k] - thh[j]);
                float A = adx + ady;      // |dcx|+|dcy|
                float B = adwh + adhh;    // (|dw|+|dh|)/2
                float sx = qhw[k] + thw[j];
                float sy = qhh[k] + thh[j];
                float mxx = fmaxf(adx, adwh);
                float mxy = fmaxf(ady, adhh);
                float iwr = sx - mxx, ihr = sy - mxy;
                float iw = fmaxf(iwr, 0.0f), ih = fmaxf(ihr, 0.0f);
                float inter = iw * ih;
                float ew = sx + mxx, eh = sy + mxy;
                float earea = ew * eh;
                float uni = (qa[k] + ta[j]) - inter;
                // X = inter/uni + uni/earea with a single rcp
                float rr = __builtin_amdgcn_rcpf(uni * earea);
                float X = fmaf(uni, uni, inter * earea) * rr;
                float c2 = 2.0f - s_prob[ql][(labw >> (8 * j)) & 0xff];
                // C = 5*(A+2B) - cls + 2 - 2*X
                r[j] = fmaf(-2.0f, X, fmaf(5.0f, A, fmaf(10.0f, B, c2)));
            }
            // non-temporal: output is write-once, keep it out of L2
            __builtin_nontemporal_store(r,
                (f32x4*)(out + (size_t)(q0 + ql) * NM) + g);
        }
    }
}

extern "C" void kernel_launch(void* const* d_in, const int* in_sizes, int n_in,
                              void* d_out, int out_size, void* d_ws, size_t ws_size,
                              hipStream_t stream) {
    const float* logits  = (const float*)d_in[0];
    const float* pboxes  = (const float*)d_in[1];
    const int*   tlabels = (const int*)d_in[2];
    const float* tboxes  = (const float*)d_in[3];
    float* out = (float*)d_out;

    const int BQ = in_sizes[1] / 4;   // 14400
    const int grid = BQ / QT;         // 1800
    matcher_cost_kernel<<<grid, BLOCK, 0, stream>>>(logits, pboxes, tlabels, tboxes, out);
}

// Round 7
// 30.739 us; speedup vs baseline: 2.4406x; 1.0159x over previous
//
#include <hip/hip_runtime.h>

#define QT 8             // queries per block (2 per wave)
#define NM 1600
#define NG (NM / 4)      // 400 groups of 4 targets
#define NC 91
#define BLOCK 256

typedef float f32x4 __attribute__((ext_vector_type(4)));
typedef float f32x2 __attribute__((ext_vector_type(2)));

__global__ __launch_bounds__(BLOCK, 5) void matcher_cost_kernel(
    const float* __restrict__ logits,   // [BQ, 91]
    const float* __restrict__ pboxes,   // [BQ, 4] cxcywh
    const int*   __restrict__ tlabels,  // [1600]
    const float* __restrict__ tboxes,   // [1600, 4] cxcywh
    float* __restrict__ out)            // [BQ, 1600]
{
    // SoA half-width staging + packed-u8 labels + per-block (2 - prob) table.
    __shared__ float4 s_cx[NG], s_cy[NG], s_hw[NG], s_hh[NG]; // 25600 B
    __shared__ unsigned s_lab[NG];                            // 1600 B
    __shared__ float s_c2[QT][NC + 1];                        // 2944 B

    const int tid  = threadIdx.x;
    const int wv   = tid >> 6;      // wave 0..3
    const int lane = tid & 63;
    const int q0   = blockIdx.x * QT;

    // ---- stage targets AoS -> SoA (half-widths), labels -> packed u8 ----
    const float4* tb4 = (const float4*)tboxes;
    const int4*   lb4 = (const int4*)tlabels;
    for (int g = tid; g < NG; g += BLOCK) {
        float4 t0 = tb4[4 * g + 0], t1 = tb4[4 * g + 1];
        float4 t2 = tb4[4 * g + 2], t3 = tb4[4 * g + 3];
        s_cx[g] = make_float4(t0.x, t1.x, t2.x, t3.x);
        s_cy[g] = make_float4(t0.y, t1.y, t2.y, t3.y);
        s_hw[g] = make_float4(0.5f * t0.z, 0.5f * t1.z, 0.5f * t2.z, 0.5f * t3.z);
        s_hh[g] = make_float4(0.5f * t0.w, 0.5f * t1.w, 0.5f * t2.w, 0.5f * t3.w);
        int4 vl = lb4[g];
        s_lab[g] = (unsigned)(vl.x & 0xff) | ((unsigned)(vl.y & 0xff) << 8)
                 | ((unsigned)(vl.z & 0xff) << 16) | ((unsigned)(vl.w & 0xff) << 24);
    }

    // ---- softmax: wave wv computes queries q0+2*wv, q0+2*wv+1; stores 2-p ----
    #pragma unroll
    for (int k = 0; k < 2; ++k) {
        const int ql = 2 * wv + k;
        const float* lrow = logits + (size_t)(q0 + ql) * NC;
        float v0 = (lane      < NC) ? lrow[lane]      : -3.4e38f;
        float v1 = (lane + 64 < NC) ? lrow[lane + 64] : -3.4e38f;
        float mx = fmaxf(v0, v1);
        #pragma unroll
        for (int off = 32; off; off >>= 1) mx = fmaxf(mx, __shfl_xor(mx, off));
        float e0 = (lane      < NC) ? __expf(v0 - mx) : 0.0f;
        float e1 = (lane + 64 < NC) ? __expf(v1 - mx) : 0.0f;
        float s = e0 + e1;
        #pragma unroll
        for (int off = 32; off; off >>= 1) s += __shfl_xor(s, off);
        float inv = 1.0f / s;
        if (lane      < NC) s_c2[ql][lane]      = 2.0f - e0 * inv;
        if (lane + 64 < NC) s_c2[ql][lane + 64] = 2.0f - e1 * inv;
    }

    // ---- query constants as f32x2 splats (half-width form) ----
    f32x2 qcx[2], qcy[2], qhw[2], qhh[2], qa[2];
    #pragma unroll
    for (int k = 0; k < 2; ++k) {
        float4 pb = ((const float4*)pboxes)[q0 + 2 * wv + k];
        qcx[k] = (f32x2){pb.x, pb.x};
        qcy[k] = (f32x2){pb.y, pb.y};
        qhw[k] = (f32x2){0.5f * pb.z, 0.5f * pb.z};
        qhh[k] = (f32x2){0.5f * pb.w, 0.5f * pb.w};
        float a = pb.z * pb.w;
        qa[k]  = (f32x2){a, a};
    }

    __syncthreads();

    const f32x2 zero2 = {0.0f, 0.0f};

    // ---- sweep: packed f32x2 math, 2 target-pairs per op, 2 queries/wave ----
    for (int g = lane; g < NG; g += 64) {
        float4 vcx = s_cx[g], vcy = s_cy[g], vhw = s_hw[g], vhh = s_hh[g];
        unsigned labw = s_lab[g];
        f32x2 tcx[2] = {{vcx.x, vcx.y}, {vcx.z, vcx.w}};
        f32x2 tcy[2] = {{vcy.x, vcy.y}, {vcy.z, vcy.w}};
        f32x2 thw[2] = {{vhw.x, vhw.y}, {vhw.z, vhw.w}};
        f32x2 thh[2] = {{vhh.x, vhh.y}, {vhh.z, vhh.w}};
        f32x2 ta[2];
        #pragma unroll
        for (int h = 0; h < 2; ++h) ta[h] = 4.0f * (thw[h] * thh[h]);

        #pragma unroll
        for (int k = 0; k < 2; ++k) {
            const int ql = 2 * wv + k;
            const float* tab = s_c2[ql];
            f32x2 rr2[2];
            #pragma unroll
            for (int h = 0; h < 2; ++h) {
                f32x2 adx = __builtin_elementwise_abs(qcx[k] - tcx[h]);
                f32x2 ady = __builtin_elementwise_abs(qcy[k] - tcy[h]);
                f32x2 adw = __builtin_elementwise_abs(qhw[k] - thw[h]);
                f32x2 adh = __builtin_elementwise_abs(qhh[k] - thh[h]);
                f32x2 A = adx + ady;            // |dcx|+|dcy|
                f32x2 B = adw + adh;            // (|dw|+|dh|)/2
                f32x2 sx = qhw[k] + thw[h];
                f32x2 sy = qhh[k] + thh[h];
                f32x2 mxx = __builtin_elementwise_max(adx, adw);
                f32x2 mxy = __builtin_elementwise_max(ady, adh);
                f32x2 iw = __builtin_elementwise_max(sx - mxx, zero2);
                f32x2 ih = __builtin_elementwise_max(sy - mxy, zero2);
                f32x2 inter = iw * ih;
                f32x2 earea = (sx + mxx) * (sy + mxy);
                f32x2 uni = (qa[k] + ta[h]) - inter;
                f32x2 ue = uni * earea;
                f32x2 rr = {__builtin_amdgcn_rcpf(ue[0]),
                            __builtin_amdgcn_rcpf(ue[1])};
                f32x2 X = (uni * uni + inter * earea) * rr;
                f32x2 c2 = {tab[(labw >> (16 * h)) & 0xff],
                            tab[(labw >> (16 * h + 8)) & 0xff]};
                rr2[h] = -2.0f * X + (5.0f * A + (10.0f * B + c2));
            }
            f32x4 r4 = {rr2[0][0], rr2[0][1], rr2[1][0], rr2[1][1]};
            __builtin_nontemporal_store(r4,
                (f32x4*)(out + (size_t)(q0 + ql) * NM) + g);
        }
    }
}

extern "C" void kernel_launch(void* const* d_in, const int* in_sizes, int n_in,
                              void* d_out, int out_size, void* d_ws, size_t ws_size,
                              hipStream_t stream) {
    const float* logits  = (const float*)d_in[0];
    const float* pboxes  = (const float*)d_in[1];
    const int*   tlabels = (const int*)d_in[2];
    const float* tboxes  = (const float*)d_in[3];
    float* out = (float*)d_out;

    const int BQ = in_sizes[1] / 4;   // 14400
    const int grid = BQ / QT;         // 1800
    matcher_cost_kernel<<<grid, BLOCK, 0, stream>>>(logits, pboxes, tlabels, tboxes, out);
}